// Round 15
// baseline (85.922 us; speedup 1.0000x reference)
//
#include <hip/hip_runtime.h>
#include <hip/hip_bf16.h>

typedef float f32x4 __attribute__((ext_vector_type(4)));
typedef __bf16 bf16x8 __attribute__((ext_vector_type(8)));
typedef __bf16 bf16x4 __attribute__((ext_vector_type(4)));

__device__ __forceinline__ void gload_lds16(const __bf16* g, __bf16* l) {
  __builtin_amdgcn_global_load_lds(
      (const __attribute__((address_space(1))) void*)g,
      (__attribute__((address_space(3))) void*)l, 16, 0, 0);
}

// ---------------------------------------------------------------------------
// convert: fp32 -> bf16 for x (2M elems) and Wq/Wk/Wv/Wo (1M each)
// ---------------------------------------------------------------------------
__global__ __launch_bounds__(256) void convert_all(
    const float* __restrict__ x, const float* __restrict__ wq,
    const float* __restrict__ wk, const float* __restrict__ wv,
    const float* __restrict__ wo, __bf16* __restrict__ dst)
{
  int t = blockIdx.x * 256 + threadIdx.x;
  const float* src; size_t soff;
  if (t < 262144) { src = x; soff = (size_t)t * 8; }
  else {
    int r = (t - 262144) >> 17;
    src = (r == 0) ? wq : (r == 1) ? wk : (r == 2) ? wv : wo;
    soff = (size_t)((t - 262144) & 131071) * 8;
  }
  float4 f0 = *(const float4*)(src + soff);
  float4 f1 = *(const float4*)(src + soff + 4);
  bf16x8 o;
  o[0]=(__bf16)f0.x; o[1]=(__bf16)f0.y; o[2]=(__bf16)f0.z; o[3]=(__bf16)f0.w;
  o[4]=(__bf16)f1.x; o[5]=(__bf16)f1.y; o[6]=(__bf16)f1.z; o[7]=(__bf16)f1.w;
  *(bf16x8*)(dst + (size_t)t * 8) = o;
}

// ---------------------------------------------------------------------------
// GEMM: C[m][n] = sum_k A[m][k] * B[n][k].  Tile BM x BN, BK=64.
// global_load_lds w=16; swizzle contract: LDS slot s of row holds global
// chunk s^(row&7) (established by staging chunk lc^(row&7) at slot lc).
// ROPE=true (QKV, BN=128): z<2 epilogue = RoPE + justnorm + sqk in fp32.
// MERGE=true (out-proj): bm>=16 blocks reg-stage A = (oA+oB)/(lA+lB) from
// scratch (fused flash-merge; head index == kt because BK=64). The reg-staged
// write honors the same swizzle contract: read chunk (l&7)^(row&7), store at
// slot (l&7).  [round-14 bug: stored chunk ch at slot ch -- identity]
// ---------------------------------------------------------------------------
template <int BM, int BN, int BK, typename OutT, bool ROPE, bool MERGE>
__global__ __launch_bounds__(256) void gemm_bt(
    const __bf16* __restrict__ A,
    const __bf16* __restrict__ B0, const __bf16* __restrict__ B1, const __bf16* __restrict__ B2,
    OutT* __restrict__ C0, OutT* __restrict__ C1, OutT* __restrict__ C2,
    int M, int N, int K, const float* __restrict__ sqkp,
    const float* __restrict__ oS, const float* __restrict__ lS)
{
  const __bf16* B = (blockIdx.z == 0) ? B0 : (blockIdx.z == 1) ? B1 : B2;
  OutT* C = (blockIdx.z == 0) ? C0 : (blockIdx.z == 1) ? C1 : C2;

  constexpr int MT = BM / 32, NT = BN / 32, KK = BK / 32;
  constexpr int CPR = BK / 8;          // 16B chunks per row
  constexpr int RPI = 64 / CPR;        // rows per gload inst
  __shared__ __align__(16) __bf16 As[BM * BK];
  __shared__ __align__(16) __bf16 Bs[BN * BK];

  const int tid = threadIdx.x, w = tid >> 6, l = tid & 63;
  const int wr = w >> 1, wc = w & 1;
  const int g = l >> 4, c16 = l & 15;
  const int bm = blockIdx.y, bn = blockIdx.x;
  const int lr = l / CPR, lc = l % CPR;

  f32x4 acc[MT][NT] = {};
  const int nk = K / BK;
  const bool amerge = MERGE && (bm >= 16);

  for (int kt = 0; kt < nk; ++kt) {
    __syncthreads();
    if (amerge) {
      // fused flash-merge A staging: rows bm*64..+63 come from oS/lS scratch
#pragma unroll
      for (int ii = 0; ii < 2; ++ii) {
        int row = (w + ii * 4) * 8 + (l >> 3);
        int sr = bm * 64 + row - 1024;
        int ch = (l & 7) ^ (row & 7);            // global chunk for slot (l&7)
        const float* pa0 = oS + (size_t)sr * 1024 + kt * 64 + ch * 8;
        f32x4 a0 = *(const f32x4*)(pa0);
        f32x4 a1 = *(const f32x4*)(pa0 + 4);
        f32x4 b0 = *(const f32x4*)(pa0 + 1024 * 1024);
        f32x4 b1 = *(const f32x4*)(pa0 + 1024 * 1024 + 4);
        float rinv = 1.0f / (lS[(size_t)sr * 16 + kt] + lS[(size_t)16384 + sr * 16 + kt]);
        a0 = (a0 + b0) * rinv;
        a1 = (a1 + b1) * rinv;
        bf16x8 pk;
        pk[0]=(__bf16)a0[0]; pk[1]=(__bf16)a0[1]; pk[2]=(__bf16)a0[2]; pk[3]=(__bf16)a0[3];
        pk[4]=(__bf16)a1[0]; pk[5]=(__bf16)a1[1]; pk[6]=(__bf16)a1[2]; pk[7]=(__bf16)a1[3];
        *(bf16x8*)(As + row * BK + (l & 7) * 8) = pk;   // slot = l&7 (FIX)
      }
    } else {
#pragma unroll
      for (int i = w; i < BM / RPI; i += 4) {
        int row = i * RPI + lr;
        int sch = lc ^ (row & 7);
        gload_lds16(A + (size_t)(bm * BM + row) * K + kt * BK + sch * 8, As + i * RPI * BK);
      }
    }
#pragma unroll
    for (int i = w; i < BN / RPI; i += 4) {
      int row = i * RPI + lr;
      int sch = lc ^ (row & 7);
      gload_lds16(B + (size_t)(bn * BN + row) * K + kt * BK + sch * 8, Bs + i * RPI * BK);
    }
    __syncthreads();

#pragma unroll
    for (int kk = 0; kk < KK; ++kk) {
      bf16x8 af[MT], bf[NT];
#pragma unroll
      for (int mt = 0; mt < MT; ++mt) {
        int row = wr * (BM / 2) + mt * 16 + c16;
        af[mt] = *(const bf16x8*)(As + row * BK + (((kk * 4 + g) ^ (row & 7)) * 8));
      }
#pragma unroll
      for (int nt = 0; nt < NT; ++nt) {
        int row = wc * (BN / 2) + nt * 16 + c16;
        bf[nt] = *(const bf16x8*)(Bs + row * BK + (((kk * 4 + g) ^ (row & 7)) * 8));
      }
#pragma unroll
      for (int mt = 0; mt < MT; ++mt)
#pragma unroll
        for (int nt = 0; nt < NT; ++nt)
          acc[mt][nt] = __builtin_amdgcn_mfma_f32_16x16x32_bf16(af[mt], bf[nt], acc[mt][nt], 0, 0, 0);
    }
  }

  bool done = false;
  if constexpr (ROPE) {
    static_assert(!ROPE || NT == 4, "ROPE epilogue assumes BN=128");
    if (blockIdx.z < 2) {
      const bool isQ = (blockIdx.z == 0);
      const int hcol = bn * BN + wc * (BN / 2);
      float sq[4];
#pragma unroll
      for (int nt = 0; nt < 4; ++nt) sq[nt] = sqkp[hcol + nt * 16 + c16] * 32.0f;
      const float QSC = 8.0f * 1.4426950408889634f;      // sqrt(64)*log2(e)
      const float L = 0.415241011860919f;                // log2(10000)/32
      const float inv0 = exp2f(-(float)c16 * L);
      const float inv1 = exp2f(-(float)(c16 + 16) * L);
#pragma unroll
      for (int mt = 0; mt < MT; ++mt) {
#pragma unroll
        for (int r = 0; r < 4; ++r) {
          int row = bm * BM + wr * (BM / 2) + mt * 16 + g * 4 + r;
          float s0, c0, s1, c1;
          sincosf((float)row * inv0, &s0, &c0);
          sincosf((float)row * inv1, &s1, &c1);
          float v0 = acc[mt][0][r], v1 = acc[mt][1][r];
          float v2 = acc[mt][2][r], v3 = acc[mt][3][r];
          float n0 = v0 * c0 - v2 * s0;
          float n2 = v0 * s0 + v2 * c0;
          float n1 = v1 * c1 - v3 * s1;
          float n3 = v1 * s1 + v3 * c1;
          float ss = n0 * n0 + n1 * n1 + n2 * n2 + n3 * n3;
#pragma unroll
          for (int m2 = 1; m2 < 16; m2 <<= 1) ss += __shfl_xor(ss, m2, 16);
          float rinv = rsqrtf(ss);
          if (isQ) rinv *= QSC;
          C[(size_t)row * N + hcol +  0 + c16] = (OutT)(n0 * sq[0] * rinv);
          C[(size_t)row * N + hcol + 16 + c16] = (OutT)(n1 * sq[1] * rinv);
          C[(size_t)row * N + hcol + 32 + c16] = (OutT)(n2 * sq[2] * rinv);
          C[(size_t)row * N + hcol + 48 + c16] = (OutT)(n3 * sq[3] * rinv);
        }
      }
      done = true;
    }
  }
  if (!done) {
#pragma unroll
    for (int mt = 0; mt < MT; ++mt)
#pragma unroll
      for (int nt = 0; nt < NT; ++nt)
#pragma unroll
        for (int r = 0; r < 4; ++r) {
          int row = bm * BM + wr * (BM / 2) + mt * 16 + g * 4 + r;
          int col = bn * BN + wc * (BN / 2) + nt * 16 + c16;
          C[(size_t)row * N + col] = (OutT)acc[mt][nt][r];
        }
  }
}

// ---------------------------------------------------------------------------
// V transpose: vt[h][d][n] = v[n][h*64+d]
// ---------------------------------------------------------------------------
__global__ __launch_bounds__(256) void vtrans(const __bf16* __restrict__ v, __bf16* __restrict__ vt)
{
  __shared__ __align__(16) __bf16 t[64 * 72];
  int h = blockIdx.y;
  int n0 = blockIdx.x * 64;
  int tid = threadIdx.x;
#pragma unroll
  for (int j = 0; j < 2; ++j) {
    int idx = tid + j * 256;
    int r = idx >> 3, c = (idx & 7) * 8;
    bf16x8 val = *(const bf16x8*)(v + (size_t)(n0 + r) * 1024 + h * 64 + c);
    *(bf16x8*)&t[r * 72 + c] = val;
  }
  __syncthreads();
#pragma unroll
  for (int j = 0; j < 2; ++j) {
    int idx = tid + j * 256;
    int d = idx >> 3, nn = (idx & 7) * 8;
    bf16x8 o;
#pragma unroll
    for (int jj = 0; jj < 8; ++jj) o[jj] = t[(nn + jj) * 72 + d];
    *(bf16x8*)(vt + (size_t)(h * 64 + d) * 2048 + n0 + nn) = o;
  }
}

// ---------------------------------------------------------------------------
// Flash attention, block-shared KV, 2-way KV-SPLIT, swapped QK^T, Ps-swizzle,
// ones-MFMA row sums. Counted-vmcnt double barrier per tile (T4):
//   s_barrier (#1) ; STAGE(kt+1) ; s_waitcnt vmcnt(4) ; s_barrier (#2) ; compute.
// vmcnt(4) waits only STAGE(kt) (issued a tile ago); kt+1's 4 loads fly.
// ---------------------------------------------------------------------------
#define STAGE(BUF, KT)                                                         \
  {                                                                            \
    _Pragma("unroll")                                                          \
    for (int p = 0; p < 2; ++p) {                                              \
      int row = srow + p * 32;                                                 \
      int sch = sc ^ (row & 7);                                                \
      gload_lds16(Kg + (size_t)((KT) * 64 + row) * 1024 + h * 64 + sch * 8,    \
                  &Ks[BUF][w * 512 + p * 2048]);                               \
      gload_lds16(Vg + ((size_t)h * 64 + row) * 2048 + (KT) * 64 + sch * 8,    \
                  &Vs[BUF][w * 512 + p * 2048]);                               \
    }                                                                          \
  }

__global__ __launch_bounds__(256, 4) void attn_kernel(
    const __bf16* __restrict__ Qg, const __bf16* __restrict__ Kg,
    const __bf16* __restrict__ Vg, __bf16* __restrict__ Og,
    float* __restrict__ oS, float* __restrict__ lS)
{
  __shared__ __align__(16) __bf16 Ks[2][4096];   // 16 KB
  __shared__ __align__(16) __bf16 Vs[2][4096];   // 16 KB
  __shared__ __align__(16) __bf16 Ps[4][1024];   //  8 KB  -> total 40 KB

  const int b = blockIdx.x;
  int h, qt, kts, kte, sidx;
  if (b < 512) {
    int p = b >> 5;
    qt = 16 + p;
    sidx = (b >> 4) & 1;
    h = b & 15;
    int mid = (qt + 1) >> 1;
    kts = sidx ? mid : 0;
    kte = sidx ? qt : (mid - 1);
  } else {
    qt = 15 - ((b - 512) >> 4);
    h = b & 15;
    kts = 0; kte = qt; sidx = -1;
  }
  const int q0 = qt * 64;

  const int tid = threadIdx.x, w = tid >> 6, l = tid & 63;
  const int g = l >> 4, c16 = l & 15;
  const int srow = tid >> 3;
  const int sc   = tid & 7;
  const int swz  = (c16 & 7) << 4;           // Ps row-XOR swizzle

  __bf16* Ps_w = &Ps[w][0];
  const int qig = q0 + w * 16 + c16;         // this thread's q-row in S^T

  const __bf16* qbase = Qg + (size_t)qig * 1024 + h * 64 + g * 8;
  const bf16x8 qf0 = *(const bf16x8*)(qbase);
  const bf16x8 qf1 = *(const bf16x8*)(qbase + 32);

  bf16x8 onesf;
#pragma unroll
  for (int j = 0; j < 8; ++j) onesf[j] = (__bf16)1.0f;

  f32x4 o[4] = {};
  f32x4 ol = {};                             // row sums via ones-MFMA

  STAGE(0, kts)

  for (int kt = kts; kt <= kte; ++kt) {
    const int cur = (kt - kts) & 1;
    __builtin_amdgcn_s_barrier();            // #1: all waves done reading buf(cur^1)
    __builtin_amdgcn_sched_barrier(0);
    if (kt < kte) {
      STAGE(cur ^ 1, kt + 1)
      asm volatile("s_waitcnt vmcnt(4)" ::: "memory");  // STAGE(kt) landed; kt+1 flies
    } else {
      asm volatile("s_waitcnt vmcnt(0)" ::: "memory");
    }
    __builtin_amdgcn_s_barrier();            // #2: everyone's tile-kt data visible
    __builtin_amdgcn_sched_barrier(0);

    const __bf16* Kb = Ks[cur];
    const __bf16* Vb = Vs[cur];

    // S^T = K Q^T : s[kjb][r] = S[qi=c16][kj = kjb*16 + g*4 + r]
    f32x4 s[4] = {};
#pragma unroll
    for (int kjb = 0; kjb < 4; ++kjb) {
      int r = kjb * 16 + c16;
      bf16x8 k0 = *(const bf16x8*)((char*)Kb + r * 128 + ((g ^ (r & 7)) * 16));
      bf16x8 k1 = *(const bf16x8*)((char*)Kb + r * 128 + (((4 + g) ^ (r & 7)) * 16));
      s[kjb] = __builtin_amdgcn_mfma_f32_16x16x32_bf16(k0, qf0, s[kjb], 0, 0, 0);
      s[kjb] = __builtin_amdgcn_mfma_f32_16x16x32_bf16(k1, qf1, s[kjb], 0, 0, 0);
    }

    // P = exp2(S): 4 contiguous bf16 per kjb -> swizzled b64 writes
    const bool diag = (kt == qt);
#pragma unroll
    for (int kjb = 0; kjb < 4; ++kjb) {
      bf16x4 pk;
#pragma unroll
      for (int r = 0; r < 4; ++r) {
        float sv = s[kjb][r];
        int kvg = kt * 64 + kjb * 16 + g * 4 + r;
        if (diag && kvg > qig) sv = -1e30f;
        pk[r] = (__bf16)exp2f(sv);
      }
      int pbyte = (c16 * 128 + kjb * 32 + g * 8) ^ swz;
      *(bf16x4*)((char*)Ps_w + pbyte) = pk;
    }

    // O += P V ; ol += P * 1  (row sums, same D-layout as o)
#pragma unroll
    for (int ks = 0; ks < 2; ++ks) {
      int abyte = (c16 * 128 + ks * 64 + g * 16) ^ swz;
      bf16x8 pa = *(const bf16x8*)((char*)Ps_w + abyte);
#pragma unroll
      for (int nt = 0; nt < 4; ++nt) {
        int r = nt * 16 + c16;
        bf16x8 vb = *(const bf16x8*)((char*)Vb + r * 128 + (((ks * 4 + g) ^ (r & 7)) * 16));
        o[nt] = __builtin_amdgcn_mfma_f32_16x16x32_bf16(pa, vb, o[nt], 0, 0, 0);
      }
      ol = __builtin_amdgcn_mfma_f32_16x16x32_bf16(pa, onesf, ol, 0, 0, 0);
    }
  }

  if (sidx < 0) {
    // o[nt][r] is row g*4+r, col nt*16+c16 ; ol[r] is that row's sum
#pragma unroll
    for (int r = 0; r < 4; ++r) {
      float rinv = 1.0f / ol[r];
      int qi = q0 + w * 16 + g * 4 + r;
#pragma unroll
      for (int nt = 0; nt < 4; ++nt)
        Og[(size_t)qi * 1024 + h * 64 + nt * 16 + c16] = (__bf16)(o[nt][r] * rinv);
    }
  } else {
    float* oBase = oS + (size_t)sidx * 1024 * 1024;
#pragma unroll
    for (int r = 0; r < 4; ++r) {
      int row = q0 + w * 16 + g * 4 + r - 1024;
#pragma unroll
      for (int nt = 0; nt < 4; ++nt)
        oBase[(size_t)row * 1024 + h * 64 + nt * 16 + c16] = o[nt][r];
      if (c16 == 0)
        lS[(size_t)sidx * 1024 * 16 + (size_t)row * 16 + h] = ol[r];
    }
  }
}

// ---------------------------------------------------------------------------
extern "C" void kernel_launch(void* const* d_in, const int* in_sizes, int n_in,
                              void* d_out, int out_size, void* d_ws, size_t ws_size,
                              hipStream_t stream) {
  const float* x   = (const float*)d_in[0];
  const float* Wq  = (const float*)d_in[1];
  const float* Wk  = (const float*)d_in[2];
  const float* Wv  = (const float*)d_in[3];
  const float* Wo  = (const float*)d_in[4];
  const float* sqk = (const float*)d_in[5];
  float* out = (float*)d_out;

  __bf16* xb  = (__bf16*)d_ws;                  // [2048][1024]
  __bf16* wqb = xb  + (size_t)2048 * 1024;      // [1024][1024]
  __bf16* wkb = wqb + (size_t)1024 * 1024;
  __bf16* wvb = wkb + (size_t)1024 * 1024;
  __bf16* wob = wvb + (size_t)1024 * 1024;
  __bf16* qn  = wob + (size_t)1024 * 1024;      // [2048][1024] rope+norm'd q
  __bf16* kn  = qn  + (size_t)2048 * 1024;      // [2048][1024] rope+norm'd k
  __bf16* v   = kn  + (size_t)2048 * 1024;      // [2048][1024]
  __bf16* vtb = v   + (size_t)2048 * 1024;      // [16][64][2048]
  __bf16* og  = vtb + (size_t)2048 * 1024;      // [2048][1024] (rows <1024 used)
  float*  oS  = (float*)(og + (size_t)2048 * 1024);  // [2][1024][1024] f32
  float*  lS  = oS + (size_t)2 * 1024 * 1024;        // [2][1024][16]  f32

  convert_all<<<3072, 256, 0, stream>>>(x, Wq, Wk, Wv, Wo, xb);
  gemm_bt<64, 128, 64, __bf16, true, false><<<dim3(8, 32, 3), 256, 0, stream>>>(
      xb, wqb, wkb, wvb, qn, kn, v, 2048, 1024, 1024, sqk, nullptr, nullptr);
  vtrans<<<dim3(32, 16), 256, 0, stream>>>(v, vtb);
  attn_kernel<<<768, 256, 0, stream>>>(qn, kn, vtb, og, oS, lS);
  gemm_bt<64, 64, 64, float, false, true><<<dim3(16, 32, 1), 256, 0, stream>>>(
      og, wob, wob, wob, out, out, out, 2048, 1024, 1024, nullptr, oS, lS);
}

// Round 16
// 73.867 us; speedup vs baseline: 1.1632x; 1.1632x over previous
//
#include <hip/hip_runtime.h>
#include <hip/hip_bf16.h>

typedef float f32x4 __attribute__((ext_vector_type(4)));
typedef __bf16 bf16x8 __attribute__((ext_vector_type(8)));
typedef __bf16 bf16x4 __attribute__((ext_vector_type(4)));

__device__ __forceinline__ void gload_lds16(const __bf16* g, __bf16* l) {
  __builtin_amdgcn_global_load_lds(
      (const __attribute__((address_space(1))) void*)g,
      (__attribute__((address_space(3))) void*)l, 16, 0, 0);
}

// ---------------------------------------------------------------------------
// convert: fp32 -> bf16 for x (2M elems) and Wq/Wk/Wv/Wo (1M each)
// ---------------------------------------------------------------------------
__global__ __launch_bounds__(256) void convert_all(
    const float* __restrict__ x, const float* __restrict__ wq,
    const float* __restrict__ wk, const float* __restrict__ wv,
    const float* __restrict__ wo, __bf16* __restrict__ dst)
{
  int t = blockIdx.x * 256 + threadIdx.x;
  const float* src; size_t soff;
  if (t < 262144) { src = x; soff = (size_t)t * 8; }
  else {
    int r = (t - 262144) >> 17;
    src = (r == 0) ? wq : (r == 1) ? wk : (r == 2) ? wv : wo;
    soff = (size_t)((t - 262144) & 131071) * 8;
  }
  float4 f0 = *(const float4*)(src + soff);
  float4 f1 = *(const float4*)(src + soff + 4);
  bf16x8 o;
  o[0]=(__bf16)f0.x; o[1]=(__bf16)f0.y; o[2]=(__bf16)f0.z; o[3]=(__bf16)f0.w;
  o[4]=(__bf16)f1.x; o[5]=(__bf16)f1.y; o[6]=(__bf16)f1.z; o[7]=(__bf16)f1.w;
  *(bf16x8*)(dst + (size_t)t * 8) = o;
}

// ---------------------------------------------------------------------------
// GEMM: C[m][n] = sum_k A[m][k] * B[n][k].  Tile BM x BN, BK=128 (r12 best).
// global_load_lds w=16; swizzle contract: LDS slot s of row holds global
// chunk s^(row&7).  kk-blocked fragment reads keep VGPR low.
// ROPE=true (QKV, BM=64, BN=128):
//   z<2 : epilogue = RoPE + justnorm + sqk in fp32 (head = bn*2+wc).
//   z==2: epilogue = fused V-TRANSPOSE through the (free) staging LDS:
//         acc -> smem[head(wc)][d 64][n stride 72] (b64 writes, 2-way free)
//         -> coalesced vtb[(bn*2+h)*64+d][bm*64 + n] b128 row writes.
//         Deletes the standalone vtrans kernel and the v buffer.
// ---------------------------------------------------------------------------
template <int BM, int BN, int BK, typename OutT, bool ROPE>
__global__ __launch_bounds__(256) void gemm_bt(
    const __bf16* __restrict__ A,
    const __bf16* __restrict__ B0, const __bf16* __restrict__ B1, const __bf16* __restrict__ B2,
    OutT* __restrict__ C0, OutT* __restrict__ C1, OutT* __restrict__ C2,
    int M, int N, int K, const float* __restrict__ sqkp)
{
  const __bf16* B = (blockIdx.z == 0) ? B0 : (blockIdx.z == 1) ? B1 : B2;
  OutT* C = (blockIdx.z == 0) ? C0 : (blockIdx.z == 1) ? C1 : C2;

  constexpr int MT = BM / 32, NT = BN / 32, KK = BK / 32;
  constexpr int CPR = BK / 8;          // 16B chunks per row
  constexpr int RPI = 64 / CPR;        // rows per gload inst
  __shared__ __align__(16) __bf16 smem[BM * BK + BN * BK];
  __bf16* As = smem;
  __bf16* Bs = smem + BM * BK;

  const int tid = threadIdx.x, w = tid >> 6, l = tid & 63;
  const int wr = w >> 1, wc = w & 1;
  const int g = l >> 4, c16 = l & 15;
  const int bm = blockIdx.y, bn = blockIdx.x;
  const int lr = l / CPR, lc = l % CPR;

  f32x4 acc[MT][NT] = {};
  const int nk = K / BK;

  for (int kt = 0; kt < nk; ++kt) {
    __syncthreads();
#pragma unroll
    for (int i = w; i < BM / RPI; i += 4) {
      int row = i * RPI + lr;
      int sch = lc ^ (row & 7);
      gload_lds16(A + (size_t)(bm * BM + row) * K + kt * BK + sch * 8, As + i * RPI * BK);
    }
#pragma unroll
    for (int i = w; i < BN / RPI; i += 4) {
      int row = i * RPI + lr;
      int sch = lc ^ (row & 7);
      gload_lds16(B + (size_t)(bn * BN + row) * K + kt * BK + sch * 8, Bs + i * RPI * BK);
    }
    __syncthreads();

#pragma unroll
    for (int kk = 0; kk < KK; ++kk) {
      bf16x8 af[MT], bf[NT];
#pragma unroll
      for (int mt = 0; mt < MT; ++mt) {
        int row = wr * (BM / 2) + mt * 16 + c16;
        af[mt] = *(const bf16x8*)(As + row * BK + (((kk * 4 + g) ^ (row & 7)) * 8));
      }
#pragma unroll
      for (int nt = 0; nt < NT; ++nt) {
        int row = wc * (BN / 2) + nt * 16 + c16;
        bf[nt] = *(const bf16x8*)(Bs + row * BK + (((kk * 4 + g) ^ (row & 7)) * 8));
      }
#pragma unroll
      for (int mt = 0; mt < MT; ++mt)
#pragma unroll
        for (int nt = 0; nt < NT; ++nt)
          acc[mt][nt] = __builtin_amdgcn_mfma_f32_16x16x32_bf16(af[mt], bf[nt], acc[mt][nt], 0, 0, 0);
    }
  }

  bool done = false;
  if constexpr (ROPE) {
    static_assert(!ROPE || (NT == 4 && MT == 2), "ROPE kernel assumes BM=64, BN=128");
    if (blockIdx.z == 2) {
      // ---- fused V-transpose epilogue ----
      __syncthreads();                       // all waves done reading As/Bs
#pragma unroll
      for (int mt = 0; mt < MT; ++mt)
#pragma unroll
        for (int nt = 0; nt < NT; ++nt) {
          bf16x4 pk;
#pragma unroll
          for (int r = 0; r < 4; ++r) pk[r] = (__bf16)acc[mt][nt][r];
          int n0 = wr * 32 + mt * 16 + g * 4;      // local n (row)
          int d  = nt * 16 + c16;                  // local d (col within head)
          *(bf16x4*)(smem + wc * 4608 + d * 72 + n0) = pk;
        }
      __syncthreads();
#pragma unroll
      for (int j = 0; j < 4; ++j) {
        int idx = tid + j * 256;
        int head = idx >> 9;                       // 0..1
        int rem = idx & 511;
        int d = rem >> 3;                          // 0..63
        int c8 = (rem & 7) * 8;                    // n-chunk
        bf16x8 val = *(const bf16x8*)(smem + head * 4608 + d * 72 + c8);
        *(bf16x8*)(C + (size_t)((bn * 2 + head) * 64 + d) * 2048 + bm * 64 + c8) = val;
      }
      done = true;
    } else {
      // ---- RoPE + justnorm + sqk epilogue (z<2) ----
      const bool isQ = (blockIdx.z == 0);
      const int hcol = bn * BN + wc * (BN / 2);
      float sq[4];
#pragma unroll
      for (int nt = 0; nt < 4; ++nt) sq[nt] = sqkp[hcol + nt * 16 + c16] * 32.0f;
      const float QSC = 8.0f * 1.4426950408889634f;      // sqrt(64)*log2(e)
      const float L = 0.415241011860919f;                // log2(10000)/32
      const float inv0 = exp2f(-(float)c16 * L);
      const float inv1 = exp2f(-(float)(c16 + 16) * L);
#pragma unroll
      for (int mt = 0; mt < MT; ++mt) {
#pragma unroll
        for (int r = 0; r < 4; ++r) {
          int row = bm * BM + wr * (BM / 2) + mt * 16 + g * 4 + r;
          float s0, c0, s1, c1;
          sincosf((float)row * inv0, &s0, &c0);
          sincosf((float)row * inv1, &s1, &c1);
          float v0 = acc[mt][0][r], v1 = acc[mt][1][r];
          float v2 = acc[mt][2][r], v3 = acc[mt][3][r];
          float n0 = v0 * c0 - v2 * s0;
          float n2 = v0 * s0 + v2 * c0;
          float n1 = v1 * c1 - v3 * s1;
          float n3 = v1 * s1 + v3 * c1;
          float ss = n0 * n0 + n1 * n1 + n2 * n2 + n3 * n3;
#pragma unroll
          for (int m2 = 1; m2 < 16; m2 <<= 1) ss += __shfl_xor(ss, m2, 16);
          float rinv = rsqrtf(ss);
          if (isQ) rinv *= QSC;
          C[(size_t)row * N + hcol +  0 + c16] = (OutT)(n0 * sq[0] * rinv);
          C[(size_t)row * N + hcol + 16 + c16] = (OutT)(n1 * sq[1] * rinv);
          C[(size_t)row * N + hcol + 32 + c16] = (OutT)(n2 * sq[2] * rinv);
          C[(size_t)row * N + hcol + 48 + c16] = (OutT)(n3 * sq[3] * rinv);
        }
      }
      done = true;
    }
  }
  if (!done) {
#pragma unroll
    for (int mt = 0; mt < MT; ++mt)
#pragma unroll
      for (int nt = 0; nt < NT; ++nt)
#pragma unroll
        for (int r = 0; r < 4; ++r) {
          int row = bm * BM + wr * (BM / 2) + mt * 16 + g * 4 + r;
          int col = bn * BN + wc * (BN / 2) + nt * 16 + c16;
          C[(size_t)row * N + col] = (OutT)acc[mt][nt][r];
        }
  }
}

// ---------------------------------------------------------------------------
// Flash attention (r12-exact, the best measured config): block-shared KV,
// 2-way KV-SPLIT, swapped QK^T (packed b64 P-writes), __syncthreads per tile,
// per-thread lsum + 2 shuffles, LDS publish epilogue.
// ---------------------------------------------------------------------------
#define STAGE(BUF, KT)                                                         \
  {                                                                            \
    _Pragma("unroll")                                                          \
    for (int p = 0; p < 2; ++p) {                                              \
      int row = srow + p * 32;                                                 \
      int sch = sc ^ (row & 7);                                                \
      gload_lds16(Kg + (size_t)((KT) * 64 + row) * 1024 + h * 64 + sch * 8,    \
                  &Ks[BUF][w * 512 + p * 2048]);                               \
      gload_lds16(Vg + ((size_t)h * 64 + row) * 2048 + (KT) * 64 + sch * 8,    \
                  &Vs[BUF][w * 512 + p * 2048]);                               \
    }                                                                          \
  }

__global__ __launch_bounds__(256, 4) void attn_kernel(
    const __bf16* __restrict__ Qg, const __bf16* __restrict__ Kg,
    const __bf16* __restrict__ Vg, __bf16* __restrict__ Og,
    float* __restrict__ oS, float* __restrict__ lS)
{
  __shared__ __align__(16) __bf16 Ks[2][4096];
  __shared__ __align__(16) __bf16 Vs[2][4096];
  __shared__ __align__(16) __bf16 Ps[4][16 * 72];

  const int b = blockIdx.x;
  int h, qt, kts, kte, sidx;
  if (b < 512) {
    int p = b >> 5;
    qt = 16 + p;
    sidx = (b >> 4) & 1;
    h = b & 15;
    int mid = (qt + 1) >> 1;
    kts = sidx ? mid : 0;
    kte = sidx ? qt : (mid - 1);
  } else {
    qt = 15 - ((b - 512) >> 4);
    h = b & 15;
    kts = 0; kte = qt; sidx = -1;
  }
  const int q0 = qt * 64;

  const int tid = threadIdx.x, w = tid >> 6, l = tid & 63;
  const int g = l >> 4, c16 = l & 15;
  const int srow = tid >> 3;
  const int sc   = tid & 7;

  __bf16* Ps_w = &Ps[w][0];
  const int qig = q0 + w * 16 + c16;         // this thread's q-row in S^T

  const __bf16* qbase = Qg + (size_t)qig * 1024 + h * 64 + g * 8;
  const bf16x8 qf0 = *(const bf16x8*)(qbase);
  const bf16x8 qf1 = *(const bf16x8*)(qbase + 32);

  f32x4 o[4] = {};
  float lsum = 0.f;

  STAGE(0, kts)

  for (int kt = kts; kt <= kte; ++kt) {
    const int cur = (kt - kts) & 1;
    __syncthreads();
    if (kt < kte) STAGE(cur ^ 1, kt + 1)

    const __bf16* Kb = Ks[cur];
    const __bf16* Vb = Vs[cur];

    // S^T = K Q^T : s[kjb][r] = S[qi=c16][kj = kjb*16 + g*4 + r]
    f32x4 s[4] = {};
#pragma unroll
    for (int kjb = 0; kjb < 4; ++kjb) {
      int r = kjb * 16 + c16;
      bf16x8 k0 = *(const bf16x8*)((char*)Kb + r * 128 + ((g ^ (r & 7)) * 16));
      bf16x8 k1 = *(const bf16x8*)((char*)Kb + r * 128 + (((4 + g) ^ (r & 7)) * 16));
      s[kjb] = __builtin_amdgcn_mfma_f32_16x16x32_bf16(k0, qf0, s[kjb], 0, 0, 0);
      s[kjb] = __builtin_amdgcn_mfma_f32_16x16x32_bf16(k1, qf1, s[kjb], 0, 0, 0);
    }

    // P = exp2(S): 4 contiguous bf16 per (kjb) -> packed b64 writes
    const bool diag = (kt == qt);
#pragma unroll
    for (int kjb = 0; kjb < 4; ++kjb) {
      bf16x4 pk;
#pragma unroll
      for (int r = 0; r < 4; ++r) {
        float sv = s[kjb][r];
        int kvg = kt * 64 + kjb * 16 + g * 4 + r;
        if (diag && kvg > qig) sv = -1e30f;
        float e = exp2f(sv);
        pk[r] = (__bf16)e;
        lsum += e;
      }
      *(bf16x4*)((char*)Ps_w + c16 * 144 + kjb * 32 + g * 8) = pk;
    }

    // O += P V  (pa rows c16, V^T rows d)
#pragma unroll
    for (int ks = 0; ks < 2; ++ks) {
      bf16x8 pa = *(const bf16x8*)((char*)Ps_w + c16 * 144 + ks * 64 + g * 16);
#pragma unroll
      for (int nt = 0; nt < 4; ++nt) {
        int r = nt * 16 + c16;
        bf16x8 vb = *(const bf16x8*)((char*)Vb + r * 128 + (((ks * 4 + g) ^ (r & 7)) * 16));
        o[nt] = __builtin_amdgcn_mfma_f32_16x16x32_bf16(pa, vb, o[nt], 0, 0, 0);
      }
    }
  }

  // reduce lsum over the 4 g-lanes sharing q-row c16
  lsum += __shfl_xor(lsum, 16);
  lsum += __shfl_xor(lsum, 32);

  if (sidx < 0) {
    // redistribute row sums: lane g==0 publishes row c16; all read rows g*4+r
    float* lsh = (float*)Ps_w;
    if (g == 0) lsh[c16] = lsum;
    __builtin_amdgcn_s_waitcnt(0);           // lgkmcnt(0): publish before read
#pragma unroll
    for (int r = 0; r < 4; ++r) {
      float rinv = 1.0f / lsh[g * 4 + r];
      int qi = q0 + w * 16 + g * 4 + r;
#pragma unroll
      for (int nt = 0; nt < 4; ++nt)
        Og[(size_t)qi * 1024 + h * 64 + nt * 16 + c16] = (__bf16)(o[nt][r] * rinv);
    }
  } else {
    float* oBase = oS + (size_t)sidx * 1024 * 1024;
#pragma unroll
    for (int r = 0; r < 4; ++r) {
      int row = q0 + w * 16 + g * 4 + r - 1024;
#pragma unroll
      for (int nt = 0; nt < 4; ++nt)
        oBase[(size_t)row * 1024 + h * 64 + nt * 16 + c16] = o[nt][r];
    }
    if (g == 0)
      lS[(size_t)sidx * 1024 * 16 + (size_t)(qig - 1024) * 16 + h] = lsum;
  }
}

// ---------------------------------------------------------------------------
// merge: rows 1024..2047: og = (oA + oB) / (lA + lB), bf16.
// ---------------------------------------------------------------------------
__global__ __launch_bounds__(256) void merge_halves(
    const float* __restrict__ oS, const float* __restrict__ lS,
    __bf16* __restrict__ Og)
{
  int row = blockIdx.x;
  int col = threadIdx.x * 4;
  int h = col >> 6;
  float lsum = lS[(size_t)row * 16 + h] + lS[(size_t)(1024 + row) * 16 + h];
  float rinv = 1.0f / lsum;
  f32x4 a = *(const f32x4*)(oS + (size_t)row * 1024 + col);
  f32x4 bb = *(const f32x4*)(oS + (size_t)(1024 * 1024) + (size_t)row * 1024 + col);
  f32x4 sum = a + bb;
  bf16x4 ob;
  ob[0] = (__bf16)(sum[0] * rinv); ob[1] = (__bf16)(sum[1] * rinv);
  ob[2] = (__bf16)(sum[2] * rinv); ob[3] = (__bf16)(sum[3] * rinv);
  *(bf16x4*)(Og + (size_t)(1024 + row) * 1024 + col) = ob;
}

// ---------------------------------------------------------------------------
extern "C" void kernel_launch(void* const* d_in, const int* in_sizes, int n_in,
                              void* d_out, int out_size, void* d_ws, size_t ws_size,
                              hipStream_t stream) {
  const float* x   = (const float*)d_in[0];
  const float* Wq  = (const float*)d_in[1];
  const float* Wk  = (const float*)d_in[2];
  const float* Wv  = (const float*)d_in[3];
  const float* Wo  = (const float*)d_in[4];
  const float* sqk = (const float*)d_in[5];
  float* out = (float*)d_out;

  __bf16* xb  = (__bf16*)d_ws;                  // [2048][1024]
  __bf16* wqb = xb  + (size_t)2048 * 1024;      // [1024][1024]
  __bf16* wkb = wqb + (size_t)1024 * 1024;
  __bf16* wvb = wkb + (size_t)1024 * 1024;
  __bf16* wob = wvb + (size_t)1024 * 1024;
  __bf16* qn  = wob + (size_t)1024 * 1024;      // [2048][1024] rope+norm'd q
  __bf16* kn  = qn  + (size_t)2048 * 1024;      // [2048][1024] rope+norm'd k
  __bf16* vtb = kn  + (size_t)2048 * 1024;      // [16][64][2048] V^T (from GEMM)
  __bf16* og  = vtb + (size_t)2048 * 1024;      // [2048][1024]
  float*  oS  = (float*)(og + (size_t)2048 * 1024);  // [2][1024][1024] f32
  float*  lS  = oS + (size_t)2 * 1024 * 1024;        // [2][1024][16]  f32

  convert_all<<<3072, 256, 0, stream>>>(x, Wq, Wk, Wv, Wo, xb);
  gemm_bt<64, 128, 128, __bf16, true><<<dim3(8, 32, 3), 256, 0, stream>>>(
      xb, wqb, wkb, wvb, qn, kn, vtb, 2048, 1024, 1024, sqk);
  attn_kernel<<<768, 256, 0, stream>>>(qn, kn, vtb, og, oS, lS);
  merge_halves<<<1024, 256, 0, stream>>>(oS, lS, og);
  gemm_bt<64, 64, 128, float, false><<<dim3(16, 32, 1), 256, 0, stream>>>(
      og, wob, wob, wob, out, out, out, 2048, 1024, 1024, nullptr);
}